// Round 3
// baseline (553.492 us; speedup 1.0000x reference)
//
#include <hip/hip_runtime.h>
#include <hip/hip_bf16.h>

// LightGCN forward: x0 = concat(user_emb, item_emb); 3x { x = A*x }; out = (x0+x1+x2+x3)/4.
// Sorted COO -> CSR via binary-searched row_ptr. One 64-lane wave per row,
// lane = embedding dim. x table kept in bf16 (halves gather lines, caches better);
// accumulation in fp32. cols/vals read via wave-uniform (scalar) loads -> no shfl.

#define EMB 64

typedef unsigned short u16;
typedef unsigned int   u32;

__device__ __forceinline__ u16 f2bf(float f) {      // round-to-nearest-even
    u32 u = __float_as_uint(f);
    return (u16)((u + 0x7FFFu + ((u >> 16) & 1u)) >> 16);
}
__device__ __forceinline__ float bf2f(u16 h) {
    return __uint_as_float(((u32)h) << 16);
}

__global__ void init_x_kernel(const float4* __restrict__ user,
                              const float4* __restrict__ item,
                              ushort4* __restrict__ x,
                              int n_user_vec, int n_total_vec) {
    int i = blockIdx.x * blockDim.x + threadIdx.x;
    if (i >= n_total_vec) return;
    float4 v = (i < n_user_vec) ? user[i] : item[i - n_user_vec];
    ushort4 o;
    o.x = f2bf(v.x); o.y = f2bf(v.y); o.z = f2bf(v.z); o.w = f2bf(v.w);
    x[i] = o;
}

// row_ptr[r] = lower_bound(rows, r); rows sorted.
__global__ void build_row_ptr_kernel(const int* __restrict__ rows, int nnz,
                                     int n_rows, int* __restrict__ row_ptr) {
    int r = blockIdx.x * blockDim.x + threadIdx.x;
    if (r > n_rows) return;
    int lo = 0, hi = nnz;
    while (lo < hi) {
        int mid = (lo + hi) >> 1;
        if (rows[mid] < r) lo = mid + 1; else hi = mid;
    }
    row_ptr[r] = lo;
}

// One wave per row. Wave-uniform edge walk (scalar cols/vals loads), batched
// 8-wide gathers for latency hiding. y[row] = sum_e vals[e]*x[cols[e]] (bf16 out).
__global__ void spmm_kernel(const int* __restrict__ row_ptr,
                            const int* __restrict__ cols,
                            const float* __restrict__ vals,
                            const u16* __restrict__ x,
                            u16* __restrict__ y,
                            int n_rows) {
    int lane = threadIdx.x & 63;
    int wid  = __builtin_amdgcn_readfirstlane(
                   blockIdx.x * (blockDim.x >> 6) + (threadIdx.x >> 6));
    if (wid >= n_rows) return;

    int start = row_ptr[wid];
    int end   = row_ptr[wid + 1];

    float a = 0.0f;
    for (int base = start; base < end; base += 8) {
        float xv[8], vv[8];
#pragma unroll
        for (int k = 0; k < 8; ++k) {
            int idx = base + k;
            int ok  = idx < end;
            int j   = ok ? idx : start;          // stay in-bounds
            int c   = cols[j];                   // wave-uniform -> s_load
            float v = vals[j];                   // wave-uniform -> s_load
            vv[k] = ok ? v : 0.0f;
            xv[k] = bf2f(x[(size_t)c * EMB + lane]);  // 128B/wave gather
        }
#pragma unroll
        for (int k = 0; k < 8; ++k) a += vv[k] * xv[k];
    }

    y[(size_t)wid * EMB + lane] = f2bf(a);
}

// out = (x0 + y1 + y2 + y3) * 0.25, x0 from the exact fp32 inputs.
__global__ void finalize_kernel(const float4* __restrict__ user,
                                const float4* __restrict__ item,
                                const ushort4* __restrict__ y1,
                                const ushort4* __restrict__ y2,
                                const ushort4* __restrict__ y3,
                                float4* __restrict__ out,
                                int n_user_vec, int n_total_vec) {
    int i = blockIdx.x * blockDim.x + threadIdx.x;
    if (i >= n_total_vec) return;
    float4 v = (i < n_user_vec) ? user[i] : item[i - n_user_vec];
    ushort4 a = y1[i], b = y2[i], c = y3[i];
    float4 o;
    o.x = (v.x + bf2f(a.x) + bf2f(b.x) + bf2f(c.x)) * 0.25f;
    o.y = (v.y + bf2f(a.y) + bf2f(b.y) + bf2f(c.y)) * 0.25f;
    o.z = (v.z + bf2f(a.z) + bf2f(b.z) + bf2f(c.z)) * 0.25f;
    o.w = (v.w + bf2f(a.w) + bf2f(b.w) + bf2f(c.w)) * 0.25f;
    out[i] = o;
}

extern "C" void kernel_launch(void* const* d_in, const int* in_sizes, int n_in,
                              void* d_out, int out_size, void* d_ws, size_t ws_size,
                              hipStream_t stream) {
    const float* user_emb = (const float*)d_in[0];
    const float* item_emb = (const float*)d_in[1];
    const int*   adj_rows = (const int*)d_in[2];
    const int*   adj_cols = (const int*)d_in[3];
    const float* adj_vals = (const float*)d_in[4];

    const int n_users = in_sizes[0] / EMB;
    const int n_items = in_sizes[1] / EMB;
    const int nnz     = in_sizes[2];
    const int n       = n_users + n_items;

    char* ws = (char*)d_ws;
    size_t xbytes = (size_t)n * EMB * sizeof(u16);   // 38.4 MB each
    u16* x0 = (u16*)ws;
    u16* y1 = (u16*)(ws + xbytes);
    u16* y2 = (u16*)(ws + 2 * xbytes);
    u16* y3 = (u16*)(ws + 3 * xbytes);
    int* row_ptr = (int*)(ws + 4 * xbytes);

    int nvec = n * (EMB / 4);

    // x0 (bf16) = concat(user, item)
    init_x_kernel<<<(nvec + 255) / 256, 256, 0, stream>>>(
        (const float4*)user_emb, (const float4*)item_emb,
        (ushort4*)x0, n_users * (EMB / 4), nvec);

    // CSR row pointers from sorted rows
    build_row_ptr_kernel<<<(n + 1 + 255) / 256, 256, 0, stream>>>(
        adj_rows, nnz, n, row_ptr);

    // 3 propagation layers
    int wg_blocks = (n + 3) / 4;   // 4 waves (rows) per 256-thread block
    spmm_kernel<<<wg_blocks, 256, 0, stream>>>(row_ptr, adj_cols, adj_vals, x0, y1, n);
    spmm_kernel<<<wg_blocks, 256, 0, stream>>>(row_ptr, adj_cols, adj_vals, y1, y2, n);
    spmm_kernel<<<wg_blocks, 256, 0, stream>>>(row_ptr, adj_cols, adj_vals, y2, y3, n);

    // out = (x0_fp32 + y1 + y2 + y3) / 4
    finalize_kernel<<<(nvec + 255) / 256, 256, 0, stream>>>(
        (const float4*)user_emb, (const float4*)item_emb,
        (const ushort4*)y1, (const ushort4*)y2, (const ushort4*)y3,
        (float4*)d_out, n_users * (EMB / 4), nvec);
}

// Round 4
// 433.624 us; speedup vs baseline: 1.2764x; 1.2764x over previous
//
#include <hip/hip_runtime.h>
#include <hip/hip_bf16.h>

// LightGCN forward: x0 = concat(user_emb, item_emb); 3x { x = A*x }; out = (x0+x1+x2+x3)/4.
// Sorted COO -> CSR via binary-searched row_ptr. One 64-lane wave per row,
// lane = embedding dim. x tables in bf16 (one 128B line per gather); fp32 accum.
// Edge (col,val) pairs staged per-wave into LDS with one coalesced load, then
// broadcast to the wave via uniform-address ds_read_b64 (no shfl, no scalar loads).

#define EMB 64

typedef unsigned short u16;
typedef unsigned int   u32;

__device__ __forceinline__ u16 f2bf(float f) {      // round-to-nearest-even
    u32 u = __float_as_uint(f);
    return (u16)((u + 0x7FFFu + ((u >> 16) & 1u)) >> 16);
}
__device__ __forceinline__ float bf2f(u16 h) {
    return __uint_as_float(((u32)h) << 16);
}

__global__ void init_x_kernel(const float4* __restrict__ user,
                              const float4* __restrict__ item,
                              ushort4* __restrict__ x,
                              int n_user_vec, int n_total_vec) {
    int i = blockIdx.x * blockDim.x + threadIdx.x;
    if (i >= n_total_vec) return;
    float4 v = (i < n_user_vec) ? user[i] : item[i - n_user_vec];
    ushort4 o;
    o.x = f2bf(v.x); o.y = f2bf(v.y); o.z = f2bf(v.z); o.w = f2bf(v.w);
    x[i] = o;
}

// row_ptr[r] = lower_bound(rows, r); rows sorted.
__global__ void build_row_ptr_kernel(const int* __restrict__ rows, int nnz,
                                     int n_rows, int* __restrict__ row_ptr) {
    int r = blockIdx.x * blockDim.x + threadIdx.x;
    if (r > n_rows) return;
    int lo = 0, hi = nnz;
    while (lo < hi) {
        int mid = (lo + hi) >> 1;
        if (rows[mid] < r) lo = mid + 1; else hi = mid;
    }
    row_ptr[r] = lo;
}

// One wave per row. Per 64-edge chunk: stage (col,val) into this wave's LDS
// slot (coalesced, non-temporal), then per edge do one uniform ds_read_b64
// (hardware broadcast) + one 128B bf16 row gather, batched 8-wide.
__global__ void spmm_kernel(const int* __restrict__ row_ptr,
                            const int* __restrict__ cols,
                            const float* __restrict__ vals,
                            const u16* __restrict__ x,
                            u16* __restrict__ y,
                            int n_rows) {
    __shared__ int2 s_edge[4][64];              // 4 waves/block, 2KB total
    int lane  = threadIdx.x & 63;
    int wslot = threadIdx.x >> 6;
    int wid   = blockIdx.x * 4 + wslot;
    if (wid >= n_rows) return;

    int start = row_ptr[wid];
    int end   = row_ptr[wid + 1];

    float a = 0.0f;
    for (int base = start; base < end; base += 64) {
        int cnt = end - base;
        if (cnt > 64) cnt = 64;
        if (lane < cnt) {
            int2 e;
            e.x = __builtin_nontemporal_load(&cols[base + lane]);
            e.y = __float_as_int(__builtin_nontemporal_load(&vals[base + lane]));
            s_edge[wslot][lane] = e;
        }
        // same-wave LDS RAW: in-order LDS pipe + compiler lgkmcnt handles it.
        for (int j = 0; j < cnt; j += 8) {
            float xv[8], vv[8];
#pragma unroll
            for (int k = 0; k < 8; ++k) {
                int  jj = j + k;
                bool ok = jj < cnt;
                int2 e  = s_edge[wslot][ok ? jj : 0];   // uniform addr -> broadcast
                vv[k] = ok ? __int_as_float(e.y) : 0.0f;
                xv[k] = bf2f(x[(size_t)e.x * EMB + lane]);
            }
#pragma unroll
            for (int k = 0; k < 8; ++k) a += vv[k] * xv[k];
        }
    }

    y[(size_t)wid * EMB + lane] = f2bf(a);
}

// out = (x0_fp32 + y1 + y2 + y3) * 0.25
__global__ void finalize_kernel(const float4* __restrict__ user,
                                const float4* __restrict__ item,
                                const ushort4* __restrict__ y1,
                                const ushort4* __restrict__ y2,
                                const ushort4* __restrict__ y3,
                                float4* __restrict__ out,
                                int n_user_vec, int n_total_vec) {
    int i = blockIdx.x * blockDim.x + threadIdx.x;
    if (i >= n_total_vec) return;
    float4 v = (i < n_user_vec) ? user[i] : item[i - n_user_vec];
    ushort4 a = y1[i], b = y2[i], c = y3[i];
    float4 o;
    o.x = (v.x + bf2f(a.x) + bf2f(b.x) + bf2f(c.x)) * 0.25f;
    o.y = (v.y + bf2f(a.y) + bf2f(b.y) + bf2f(c.y)) * 0.25f;
    o.z = (v.z + bf2f(a.z) + bf2f(b.z) + bf2f(c.z)) * 0.25f;
    o.w = (v.w + bf2f(a.w) + bf2f(b.w) + bf2f(c.w)) * 0.25f;
    out[i] = o;
}

extern "C" void kernel_launch(void* const* d_in, const int* in_sizes, int n_in,
                              void* d_out, int out_size, void* d_ws, size_t ws_size,
                              hipStream_t stream) {
    const float* user_emb = (const float*)d_in[0];
    const float* item_emb = (const float*)d_in[1];
    const int*   adj_rows = (const int*)d_in[2];
    const int*   adj_cols = (const int*)d_in[3];
    const float* adj_vals = (const float*)d_in[4];

    const int n_users = in_sizes[0] / EMB;
    const int n_items = in_sizes[1] / EMB;
    const int nnz     = in_sizes[2];
    const int n       = n_users + n_items;

    char* ws = (char*)d_ws;
    size_t xbytes = (size_t)n * EMB * sizeof(u16);   // 38.4 MB each
    u16* x0 = (u16*)ws;
    u16* y1 = (u16*)(ws + xbytes);
    u16* y2 = (u16*)(ws + 2 * xbytes);
    u16* y3 = (u16*)(ws + 3 * xbytes);
    int* row_ptr = (int*)(ws + 4 * xbytes);

    int nvec = n * (EMB / 4);

    // x0 (bf16) = concat(user, item)
    init_x_kernel<<<(nvec + 255) / 256, 256, 0, stream>>>(
        (const float4*)user_emb, (const float4*)item_emb,
        (ushort4*)x0, n_users * (EMB / 4), nvec);

    // CSR row pointers from sorted rows
    build_row_ptr_kernel<<<(n + 1 + 255) / 256, 256, 0, stream>>>(
        adj_rows, nnz, n, row_ptr);

    // 3 propagation layers
    int wg_blocks = (n + 3) / 4;   // 4 waves (rows) per 256-thread block
    spmm_kernel<<<wg_blocks, 256, 0, stream>>>(row_ptr, adj_cols, adj_vals, x0, y1, n);
    spmm_kernel<<<wg_blocks, 256, 0, stream>>>(row_ptr, adj_cols, adj_vals, y1, y2, n);
    spmm_kernel<<<wg_blocks, 256, 0, stream>>>(row_ptr, adj_cols, adj_vals, y2, y3, n);

    // out = (x0_fp32 + y1 + y2 + y3) / 4
    finalize_kernel<<<(nvec + 255) / 256, 256, 0, stream>>>(
        (const float4*)user_emb, (const float4*)item_emb,
        (const ushort4*)y1, (const ushort4*)y2, (const ushort4*)y3,
        (float4*)d_out, n_users * (EMB / 4), nvec);
}

// Round 5
// 338.674 us; speedup vs baseline: 1.6343x; 1.2804x over previous
//
#include <hip/hip_runtime.h>
#include <hip/hip_bf16.h>

// LightGCN forward: x0 = concat(user_emb, item_emb); 3x { x = A*x }; out = (x0+x1+x2+x3)/4.
// Sorted COO -> CSR row_ptr (binary search). Edges pre-expanded into a PADDED
// array pe[]: row r's segment starts at row_ptr[r] + 8*r (capacity deg+8), each
// entry = {byte offset col*128, val fp32}, rows padded with {0,0} to a multiple
// of 8 -> hot loop has no bounds checks. SpMM: one wave per row, 32 lanes x
// 2 dims (packed bf16x2), two edges processed per step (half-wave each).
// Layer 3 fused with the (x0+y1+y2+y3)/4 epilogue (fp32 out).

#define EMB 64

typedef unsigned short u16;
typedef unsigned int   u32;

__device__ __forceinline__ u16 f2bf(float f) {      // round-to-nearest-even
    u32 u = __float_as_uint(f);
    return (u16)((u + 0x7FFFu + ((u >> 16) & 1u)) >> 16);
}
__device__ __forceinline__ float bflo(u32 p) { return __uint_as_float(p << 16); }
__device__ __forceinline__ float bfhi(u32 p) { return __uint_as_float(p & 0xFFFF0000u); }

__global__ void init_x_kernel(const float4* __restrict__ user,
                              const float4* __restrict__ item,
                              ushort4* __restrict__ x,
                              int n_user_vec, int n_total_vec) {
    int i = blockIdx.x * blockDim.x + threadIdx.x;
    if (i >= n_total_vec) return;
    float4 v = (i < n_user_vec) ? user[i] : item[i - n_user_vec];
    ushort4 o;
    o.x = f2bf(v.x); o.y = f2bf(v.y); o.z = f2bf(v.z); o.w = f2bf(v.w);
    x[i] = o;
}

// row_ptr[r] = lower_bound(rows, r); rows sorted.
__global__ void build_row_ptr_kernel(const int* __restrict__ rows, int nnz,
                                     int n_rows, int* __restrict__ row_ptr) {
    int r = blockIdx.x * blockDim.x + threadIdx.x;
    if (r > n_rows) return;
    int lo = 0, hi = nnz;
    while (lo < hi) {
        int mid = (lo + hi) >> 1;
        if (rows[mid] < r) lo = mid + 1; else hi = mid;
    }
    row_ptr[r] = lo;
}

// pe[e + 8*rows[e]] = {cols[e]*128, vals[e]}; last edge of each row zero-fills
// the <=7 pad slots up to the row's ceil8(deg) boundary.
__global__ void expand_kernel(const int* __restrict__ rows,
                              const int* __restrict__ cols,
                              const float* __restrict__ vals,
                              const int* __restrict__ row_ptr,
                              int nnz, int2* __restrict__ pe) {
    int e = blockIdx.x * blockDim.x + threadIdx.x;
    if (e >= nnz) return;
    int r = rows[e];
    int dst = e + 8 * r;
    int2 ent;
    ent.x = cols[e] << 7;                    // byte offset into bf16 x table
    ent.y = __float_as_int(vals[e]);
    pe[dst] = ent;
    bool last = (e == nnz - 1) || (rows[e + 1] != r);
    if (last) {
        int s   = row_ptr[r];
        int deg = e + 1 - s;
        int cnt = (deg + 7) & ~7;
        int lim = s + 8 * r + cnt;           // = ps + cnt
        int2 z; z.x = 0; z.y = 0;
        for (int j = dst + 1; j < lim; ++j) pe[j] = z;
    }
}

// One wave per row; lane = 2 dims (sub = lane&31), halves take alternating edges.
// Per step (2 edges): 1 ds_read_b64 broadcast + 1 add + 1 dword gather + 2 unpack + 2 fma.
__global__ void spmm_kernel(const int* __restrict__ row_ptr,
                            const int2* __restrict__ pe,
                            const u32* __restrict__ x,    // bf16x2 table [n*32]
                            u32* __restrict__ y,          // bf16x2 out   [n*32]
                            int n_rows) {
    __shared__ int2 s_e[4][64];
    int lane  = threadIdx.x & 63;
    int wslot = threadIdx.x >> 6;
    int sub   = lane & 31;
    int half  = lane >> 5;
    int wid   = blockIdx.x * 4 + wslot;
    if (wid >= n_rows) return;

    int s   = row_ptr[wid];
    int deg = row_ptr[wid + 1] - s;
    int cnt = (deg + 7) & ~7;
    int ps  = s + 8 * wid;

    const char* xb = (const char*)x;
    u32 lane_byte = (u32)sub * 4u;

    float a0 = 0.0f, a1 = 0.0f;
    for (int base = 0; base < cnt; base += 64) {
        int c8 = cnt - base; if (c8 > 64) c8 = 64;
        if (lane < c8) s_e[wslot][lane] = pe[ps + base + lane];
        // same-wave LDS RAW: in-order LDS pipe + compiler lgkmcnt.
        for (int j = 0; j < c8; j += 8) {
            u32 xp[4]; float vv[4];
#pragma unroll
            for (int k = 0; k < 4; ++k) {
                int2 ent = s_e[wslot][j + 2 * k + half];  // 2 bcast groups
                vv[k] = __int_as_float(ent.y);
                xp[k] = *(const u32*)(xb + ((u32)ent.x + lane_byte));
            }
#pragma unroll
            for (int k = 0; k < 4; ++k) {
                a0 = fmaf(vv[k], bflo(xp[k]), a0);
                a1 = fmaf(vv[k], bfhi(xp[k]), a1);
            }
        }
    }

    a0 += __shfl_xor(a0, 32);
    a1 += __shfl_xor(a1, 32);
    if (half == 0) {
        u32 o = ((u32)f2bf(a1) << 16) | (u32)f2bf(a0);
        y[(size_t)wid * 32 + sub] = o;
    }
}

// Layer 3 fused with epilogue: out = (x0_fp32 + y1 + y2 + A*y2) * 0.25 (fp32 out).
__global__ void spmm_final_kernel(const int* __restrict__ row_ptr,
                                  const int2* __restrict__ pe,
                                  const u32* __restrict__ x,     // gather source = y2
                                  const u32* __restrict__ y1,
                                  const u32* __restrict__ y2,
                                  const float2* __restrict__ user, // [n_users*32]
                                  const float2* __restrict__ item,
                                  float2* __restrict__ out,        // [n*32]
                                  int n_users, int n_rows) {
    __shared__ int2 s_e[4][64];
    int lane  = threadIdx.x & 63;
    int wslot = threadIdx.x >> 6;
    int sub   = lane & 31;
    int half  = lane >> 5;
    int wid   = blockIdx.x * 4 + wslot;
    if (wid >= n_rows) return;

    int s   = row_ptr[wid];
    int deg = row_ptr[wid + 1] - s;
    int cnt = (deg + 7) & ~7;
    int ps  = s + 8 * wid;

    const char* xb = (const char*)x;
    u32 lane_byte = (u32)sub * 4u;

    float a0 = 0.0f, a1 = 0.0f;
    for (int base = 0; base < cnt; base += 64) {
        int c8 = cnt - base; if (c8 > 64) c8 = 64;
        if (lane < c8) s_e[wslot][lane] = pe[ps + base + lane];
        for (int j = 0; j < c8; j += 8) {
            u32 xp[4]; float vv[4];
#pragma unroll
            for (int k = 0; k < 4; ++k) {
                int2 ent = s_e[wslot][j + 2 * k + half];
                vv[k] = __int_as_float(ent.y);
                xp[k] = *(const u32*)(xb + ((u32)ent.x + lane_byte));
            }
#pragma unroll
            for (int k = 0; k < 4; ++k) {
                a0 = fmaf(vv[k], bflo(xp[k]), a0);
                a1 = fmaf(vv[k], bfhi(xp[k]), a1);
            }
        }
    }

    a0 += __shfl_xor(a0, 32);
    a1 += __shfl_xor(a1, 32);
    if (half == 0) {
        size_t o32 = (size_t)wid * 32 + sub;
        float2 b = (wid < n_users) ? user[o32]
                                   : item[(size_t)(wid - n_users) * 32 + sub];
        u32 p1 = y1[o32], p2 = y2[o32];
        float2 r;
        r.x = (b.x + bflo(p1) + bflo(p2) + a0) * 0.25f;
        r.y = (b.y + bfhi(p1) + bfhi(p2) + a1) * 0.25f;
        out[o32] = r;
    }
}

extern "C" void kernel_launch(void* const* d_in, const int* in_sizes, int n_in,
                              void* d_out, int out_size, void* d_ws, size_t ws_size,
                              hipStream_t stream) {
    const float* user_emb = (const float*)d_in[0];
    const float* item_emb = (const float*)d_in[1];
    const int*   adj_rows = (const int*)d_in[2];
    const int*   adj_cols = (const int*)d_in[3];
    const float* adj_vals = (const float*)d_in[4];

    const int n_users = in_sizes[0] / EMB;
    const int n_items = in_sizes[1] / EMB;
    const int nnz     = in_sizes[2];
    const int n       = n_users + n_items;

    char* ws = (char*)d_ws;
    size_t xbytes  = (size_t)n * EMB * sizeof(u16);           // 38.4 MB
    size_t pebytes = ((size_t)nnz + 8 * (size_t)n) * sizeof(int2); // 43.2 MB
    u32*  x0 = (u32*)ws;
    u32*  y1 = (u32*)(ws + xbytes);
    u32*  y2 = (u32*)(ws + 2 * xbytes);
    int2* pe = (int2*)(ws + 3 * xbytes);
    int*  row_ptr = (int*)(ws + 3 * xbytes + pebytes);

    int nvec = n * (EMB / 4);

    // x0 (bf16) = concat(user, item)
    init_x_kernel<<<(nvec + 255) / 256, 256, 0, stream>>>(
        (const float4*)user_emb, (const float4*)item_emb,
        (ushort4*)x0, n_users * (EMB / 4), nvec);

    // CSR row pointers from sorted rows
    build_row_ptr_kernel<<<(n + 1 + 255) / 256, 256, 0, stream>>>(
        adj_rows, nnz, n, row_ptr);

    // padded edge array {byte_off, val}
    expand_kernel<<<(nnz + 255) / 256, 256, 0, stream>>>(
        adj_rows, adj_cols, adj_vals, row_ptr, nnz, pe);

    // layers 1,2 -> bf16 y; layer 3 fused with mean epilogue -> fp32 out
    int wg_blocks = (n + 3) / 4;
    spmm_kernel<<<wg_blocks, 256, 0, stream>>>(row_ptr, pe, x0, y1, n);
    spmm_kernel<<<wg_blocks, 256, 0, stream>>>(row_ptr, pe, y1, y2, n);
    spmm_final_kernel<<<wg_blocks, 256, 0, stream>>>(
        row_ptr, pe, y2, y1, y2,
        (const float2*)user_emb, (const float2*)item_emb,
        (float2*)d_out, n_users, n);
}